// Round 15
// baseline (1053.873 us; speedup 1.0000x reference)
//
#include <hip/hip_runtime.h>
#include <hip/hip_fp16.h>

#define NN 38332
#define NE 1200000
#define POI 38333
#define NWG 192
#define CHUNK (NE/NWG)   // 6250 exactly
#define SBLK 256         // colstats partial blocks
#define FBLK 1024        // fc1 partial blocks

__device__ __forceinline__ float lrelu01(float v){ return v > 0.f ? v : 0.01f*v; }

__device__ __forceinline__ void load8(const __half* h, int s, int c8, float* f){
  uint4 q = *(const uint4*)((const __half*)h + (size_t)s*64 + c8);
  __half2 h0 = *(__half2*)&q.x, h1 = *(__half2*)&q.y, h2 = *(__half2*)&q.z, h3 = *(__half2*)&q.w;
  float2 r0 = __half22float2(h0), r1 = __half22float2(h1), r2 = __half22float2(h2), r3 = __half22float2(h3);
  f[0]=r0.x; f[1]=r0.y; f[2]=r1.x; f[3]=r1.y; f[4]=r2.x; f[5]=r2.y; f[6]=r3.x; f[7]=r3.y;
}
__device__ __forceinline__ void load8(const float* h, int s, int c8, float* f){
  float4 a = *(const float4*)(h + (size_t)s*64 + c8);
  float4 b = *(const float4*)(h + (size_t)s*64 + c8 + 4);
  f[0]=a.x; f[1]=a.y; f[2]=a.z; f[3]=a.w; f[4]=b.x; f[5]=b.y; f[6]=b.z; f[7]=b.w;
}
__device__ __forceinline__ void store8(float* out, int n, int cb, const float* o){
  *(float4*)&out[(size_t)n*64 + cb]     = make_float4(o[0],o[1],o[2],o[3]);
  *(float4*)&out[(size_t)n*64 + cb + 4] = make_float4(o[4],o[5],o[6],o[7]);
}
__device__ __forceinline__ void store8(__half* out, int n, int cb, const float* o){
  __half2 q0 = __floats2half2_rn(o[0], o[1]);
  __half2 q1 = __floats2half2_rn(o[2], o[3]);
  __half2 q2 = __floats2half2_rn(o[4], o[5]);
  __half2 q3 = __floats2half2_rn(o[6], o[7]);
  uint4 q;
  q.x = *(unsigned*)&q0; q.y = *(unsigned*)&q1; q.z = *(unsigned*)&q2; q.w = *(unsigned*)&q3;
  *(uint4*)((__half*)out + (size_t)n*64 + cb) = q;
}

// ---------------- setup phase A: LDS-privatized histogram (ushort partials) ----------------
__global__ __launch_bounds__(1024) void k_hist(const int* __restrict__ dst,
                                               unsigned short* __restrict__ partial){
  __shared__ int hist[NN];
  for (int i = threadIdx.x; i < NN; i += 1024) hist[i] = 0;
  __syncthreads();
  int base = blockIdx.x*CHUNK;
  for (int k = threadIdx.x; k < CHUNK; k += 1024)
    atomicAdd(&hist[dst[base + k]], 1);
  __syncthreads();
  for (int i = threadIdx.x; i < NN; i += 1024)
    partial[(size_t)blockIdx.x*NN + i] = (unsigned short)hist[i];
}

__global__ __launch_bounds__(256) void k_b1(unsigned short* __restrict__ partial,
                                            int* __restrict__ counts){
  int bin = blockIdx.x*256 + threadIdx.x;
  if (bin < NN){
    int run = 0;
    for (int wg = 0; wg < NWG; ++wg){
      int v = partial[(size_t)wg*NN + bin];
      partial[(size_t)wg*NN + bin] = (unsigned short)run;
      run += v;
    }
    counts[bin] = run;
  }
}

__global__ __launch_bounds__(1024) void k_scan(const int* __restrict__ counts, int* rowptr){
  __shared__ int part[1024];
  int tid = threadIdx.x;
  const int per = (NN + 1023)/1024;   // 38
  int base = tid*per;
  int s = 0;
  for (int k = 0; k < per; k++){ int i = base + k; if (i < NN) s += counts[i]; }
  part[tid] = s;
  __syncthreads();
  for (int off = 1; off < 1024; off <<= 1){
    int v = (tid >= off) ? part[tid-off] : 0;
    __syncthreads();
    part[tid] += v;
    __syncthreads();
  }
  int run = (tid == 0) ? 0 : part[tid-1];
  for (int k = 0; k < per; k++){
    int i = base + k;
    if (i < NN){ rowptr[i] = run; run += counts[i]; }
  }
  if (tid == 1023) rowptr[NN] = run;
}

__global__ __launch_bounds__(1024) void k_scatter(const int* __restrict__ src,
                                                  const int* __restrict__ dst,
                                                  const float* __restrict__ ew,
                                                  const int* __restrict__ rowptr,
                                                  const unsigned short* __restrict__ partial,
                                                  int2* __restrict__ cw){
  __shared__ int cur[NN];
  for (int i = threadIdx.x; i < NN; i += 1024)
    cur[i] = rowptr[i] + (int)partial[(size_t)blockIdx.x*NN + i];
  __syncthreads();
  int base = blockIdx.x*CHUNK;
  for (int k = threadIdx.x; k < CHUNK; k += 1024){
    int e = base + k;
    int d = dst[e];
    int pos = atomicAdd(&cur[d], 1);
    cw[pos] = make_int2(src[e], __float_as_int(ew[e]));
  }
}

__global__ __launch_bounds__(256) void k_dinv(const int* __restrict__ rowptr,
                                              const int2* __restrict__ cw,
                                              float* __restrict__ dinv){
  int lane = threadIdx.x & 63;
  int n = blockIdx.x*4 + (threadIdx.x >> 6);   // NN % 4 == 0
  int beg = rowptr[n], end = rowptr[n+1];
  float s = 0.f;
  for (int e = beg + lane; e < end; e += 64) s += __int_as_float(cw[e].y);
  #pragma unroll
  for (int off = 32; off; off >>= 1) s += __shfl_xor(s, off);
  if (lane == 0) dinv[n] = rsqrtf(1.0f + s);
}

__global__ __launch_bounds__(256) void k_scale(const int* __restrict__ rowptr,
                                               const float* __restrict__ dinv,
                                               int2* __restrict__ cw){
  int lane = threadIdx.x & 63;
  int n = blockIdx.x*4 + (threadIdx.x >> 6);
  float dn = dinv[n];
  int beg = rowptr[n], end = rowptr[n+1];
  for (int e = beg + lane; e < end; e += 64){
    int2 p = cw[e];
    cw[e].y = __float_as_int(dinv[p.x]*__int_as_float(p.y)*dn);
  }
}

// ---------------- dense projection: 4 rows/wave ----------------
template<int K>
__global__ __launch_bounds__(256) void k_proj(const float* __restrict__ emb,
                                              const float* __restrict__ W,
                                              float* __restrict__ outp, int rows){
  int lane = threadIdx.x & 63;
  int base = __builtin_amdgcn_readfirstlane(blockIdx.x*16 + (threadIdx.x >> 6)*4);
  float acc[4] = {0.f,0.f,0.f,0.f};
  constexpr int NCH = (K + 63)/64;
  #pragma unroll
  for (int ch = 0; ch < NCH; ++ch){
    float Wreg[64];
    #pragma unroll
    for (int j = 0; j < 64; ++j)
      Wreg[j] = (ch*64 + j < K) ? W[(ch*64 + j)*64 + lane] : 0.f;
    #pragma unroll
    for (int r = 0; r < 4; ++r){
      int row = base + r;
      if (row < rows){
        const float* er = emb + (size_t)row*K + ch*64;
        #pragma unroll
        for (int j = 0; j < 64; ++j)
          if (ch*64 + j < K) acc[r] = fmaf(er[j], Wreg[j], acc[r]);
      }
    }
  }
  #pragma unroll
  for (int r = 0; r < 4; ++r){
    int row = base + r;
    if (row < rows) outp[(size_t)row*64 + lane] = acc[r];
  }
}

__global__ __launch_bounds__(256) void k_gather(const int* __restrict__ poi_idx,
                                                const int* __restrict__ cat_idx,
                                                const float* __restrict__ feat,
                                                const float* __restrict__ pproj,
                                                const float* __restrict__ cproj,
                                                const float* __restrict__ Wf,
                                                __half* __restrict__ outh){
  int i = blockIdx.x*256 + threadIdx.x;   // NN*64 % 256 == 0
  int n = i >> 6, c = i & 63;
  float f0 = feat[n*3], f1 = feat[n*3+1], f2 = feat[n*3+2];
  float v = pproj[(size_t)poi_idx[n]*64 + c] + cproj[(size_t)cat_idx[n]*64 + c];
  v = fmaf(f0, Wf[c], v);
  v = fmaf(f1, Wf[64 + c], v);
  v = fmaf(f2, Wf[128 + c], v);
  outh[i] = __float2half(v);
}

// ---------------- fused [graphnorm-residual] + 64x64 linear (+ att dots), fp16 h out ----------------
template<bool ATT, bool RESID>
__global__ __launch_bounds__(256) void k_lin64f(float* __restrict__ x,
                                                const __half* __restrict__ t,
                                                const float* __restrict__ stats,
                                                const float* __restrict__ gb,
                                                const float* __restrict__ W,
                                                const float* __restrict__ att_src,
                                                const float* __restrict__ att_dst,
                                                __half* __restrict__ h,
                                                float* __restrict__ a_s,
                                                float* __restrict__ a_d){
  int lane = threadIdx.x & 63;
  int base = blockIdx.x*32 + (threadIdx.x >> 6)*8;
  float Wreg[64];
  #pragma unroll
  for (int j = 0; j < 64; ++j) Wreg[j] = W[j*64 + lane];
  float coef = 0.f, shift = 0.f, gbv = 0.f;
  if (RESID){
    coef  = stats[128 + lane];
    shift = stats[192 + lane];
    gbv   = gb[lane];
  }
  float as_l = 0.f, ad_l = 0.f;
  if (ATT){ as_l = att_src[lane]; ad_l = att_dst[lane]; }
  #pragma unroll
  for (int r = 0; r < 8; ++r){
    int row = base + r;
    if (row < NN){
      float xn = x[(size_t)row*64 + lane];
      if (RESID){
        float tv = __half2float(t[(size_t)row*64 + lane]);
        xn += lrelu01((tv - shift)*coef + gbv);
        x[(size_t)row*64 + lane] = xn;
      }
      int xi = __float_as_int(xn);
      float acc = 0.f;
      #pragma unroll
      for (int j = 0; j < 64; ++j)
        acc = fmaf(__int_as_float(__builtin_amdgcn_readlane(xi, j)), Wreg[j], acc);
      h[(size_t)row*64 + lane] = __float2half(acc);
      if (ATT){
        float s1 = acc*as_l, s2 = acc*ad_l;
        #pragma unroll
        for (int off = 32; off; off >>= 1){ s1 += __shfl_xor(s1, off); s2 += __shfl_xor(s2, off); }
        if (lane == 0){ a_s[row] = s1; a_d[row] = s2; }
      }
    }
  }
}

// ---------------- GCN propagation: channel-split (2 blocks/node-quad), all loads up-front ----------------
template<bool DO_LRELU, typename TIN, typename TOUT>
__global__ __launch_bounds__(256) void k_gcn_prop(const TIN* __restrict__ h,
                                                  const int* __restrict__ rowptr,
                                                  const int2* __restrict__ cw,
                                                  const float* __restrict__ dinv,
                                                  const float* __restrict__ bias,
                                                  TOUT* __restrict__ out){
  int lane = threadIdx.x & 63;
  int half = blockIdx.x & 1;
  int n = __builtin_amdgcn_readfirstlane((blockIdx.x >> 1)*4 + (threadIdx.x >> 6));
  int beg = rowptr[n], end = rowptr[n+1];
  int deg = end - beg;
  int g  = lane >> 2;                  // 16 edge groups
  int co = half*32 + (lane & 3)*8;     // 8 channels per lane, 32 per half
  float acc[8] = {0.f,0.f,0.f,0.f,0.f,0.f,0.f,0.f};
  if (deg < 64){
    int sv = n; float wv = 0.f;
    if (lane < deg){
      int2 p = cw[beg + lane];
      sv = p.x; wv = __int_as_float(p.y);
    } else if (lane == deg){
      float di = dinv[n];
      wv = di*di;                      // self loop folded at slot deg
    }
    int ne = deg + 1;
    float w0 = __shfl(wv, g),      w1 = __shfl(wv, 16 + g);
    int   s0 = __shfl(sv, g),      s1 = __shfl(sv, 16 + g);
    float f0[8], f1[8];
    load8(h, s0, co, f0); load8(h, s1, co, f1);
    if (ne > 32){
      float w2 = __shfl(wv, 32 + g), w3 = __shfl(wv, 48 + g);
      int   s2 = __shfl(sv, 32 + g), s3 = __shfl(sv, 48 + g);
      float f2[8], f3[8];
      load8(h, s2, co, f2); load8(h, s3, co, f3);
      #pragma unroll
      for (int j = 0; j < 8; ++j){
        acc[j] = fmaf(w2, f2[j], acc[j]);
        acc[j] = fmaf(w3, f3[j], acc[j]);
      }
    }
    #pragma unroll
    for (int j = 0; j < 8; ++j){
      acc[j] = fmaf(w0, f0[j], acc[j]);
      acc[j] = fmaf(w1, f1[j], acc[j]);
    }
  } else {
    {
      float di = dinv[n];
      float w = (g == 0) ? di*di : 0.f;
      float f[8]; load8(h, n, co, f);
      #pragma unroll
      for (int j = 0; j < 8; ++j) acc[j] = fmaf(w, f[j], acc[j]);
    }
    int nit = (deg + 15) >> 4;
    for (int it = 0; it < nit; ++it){
      int ei = (it << 4) + g;
      int2 p = cw[beg + (ei < deg ? ei : 0)];
      float w = (ei < deg) ? __int_as_float(p.y) : 0.f;
      float f[8]; load8(h, p.x, co, f);
      #pragma unroll
      for (int j = 0; j < 8; ++j) acc[j] = fmaf(w, f[j], acc[j]);
    }
  }
  #pragma unroll
  for (int m = 4; m < 64; m <<= 1){
    #pragma unroll
    for (int j = 0; j < 8; ++j) acc[j] += __shfl_xor(acc[j], m);
  }
  if (lane < 4){
    int cb = half*32 + lane*8;
    float4 b0 = *(const float4*)&bias[cb];
    float4 b1 = *(const float4*)&bias[cb + 4];
    float o[8] = {acc[0]+b0.x, acc[1]+b0.y, acc[2]+b0.z, acc[3]+b0.w,
                  acc[4]+b1.x, acc[5]+b1.y, acc[6]+b1.z, acc[7]+b1.w};
    if (DO_LRELU){
      #pragma unroll
      for (int j = 0; j < 8; ++j) o[j] = lrelu01(o[j]);
    }
    store8(out, n, cb, o);
  }
}

// ---------------- GAT propagation: channel-split, self folded into lane array ----------------
__global__ __launch_bounds__(256) void k_gat_prop(const __half* __restrict__ h,
                                                  const int* __restrict__ rowptr,
                                                  const int2* __restrict__ cw,
                                                  const float* __restrict__ a_s,
                                                  const float* __restrict__ a_d,
                                                  const float* __restrict__ bias,
                                                  __half* __restrict__ out){
  int lane = threadIdx.x & 63;
  int half = blockIdx.x & 1;
  int n = __builtin_amdgcn_readfirstlane((blockIdx.x >> 1)*4 + (threadIdx.x >> 6));
  int beg = rowptr[n], end = rowptr[n+1];
  int deg = end - beg;
  float ad = a_d[n];
  float se = a_s[n] + ad; se = se > 0.f ? se : 0.2f*se;
  if (deg < 64){
    // self edge folded at slot `deg`
    int s = n; float v = -1e30f;
    if (lane < deg){
      s = cw[beg + lane].x;
      v = a_s[s] + ad; v = v > 0.f ? v : 0.2f*v;
    } else if (lane == deg){
      v = se;
    }
    float m = v;
    #pragma unroll
    for (int off = 32; off; off >>= 1) m = fmaxf(m, __shfl_xor(m, off));
    float ev = (lane <= deg) ? __expf(v - m) : 0.f;
    float z = ev;
    #pragma unroll
    for (int off = 32; off; off >>= 1) z += __shfl_xor(z, off);
    float zinv = 1.0f/(z + 1e-16f);
    int g = lane >> 2;
    int co = half*32 + (lane & 3)*8;
    float acc[8] = {0.f,0.f,0.f,0.f,0.f,0.f,0.f,0.f};
    int ne = deg + 1;
    float w0 = __shfl(ev, g),      w1 = __shfl(ev, 16 + g);
    int   s0 = __shfl(s, g),       s1 = __shfl(s, 16 + g);
    float f0[8], f1[8];
    load8(h, s0, co, f0); load8(h, s1, co, f1);
    if (ne > 32){
      float w2 = __shfl(ev, 32 + g), w3 = __shfl(ev, 48 + g);
      int   s2 = __shfl(s, 32 + g),  s3 = __shfl(s, 48 + g);
      float f2[8], f3[8];
      load8(h, s2, co, f2); load8(h, s3, co, f3);
      #pragma unroll
      for (int j = 0; j < 8; ++j){
        acc[j] = fmaf(w2, f2[j], acc[j]);
        acc[j] = fmaf(w3, f3[j], acc[j]);
      }
    }
    #pragma unroll
    for (int j = 0; j < 8; ++j){
      acc[j] = fmaf(w0, f0[j], acc[j]);
      acc[j] = fmaf(w1, f1[j], acc[j]);
    }
    #pragma unroll
    for (int mm = 4; mm < 64; mm <<= 1){
      #pragma unroll
      for (int j = 0; j < 8; ++j) acc[j] += __shfl_xor(acc[j], mm);
    }
    if (lane < 4){
      int cb = half*32 + lane*8;
      float4 b0 = *(const float4*)&bias[cb];
      float4 b1 = *(const float4*)&bias[cb + 4];
      float o[8] = {fmaf(acc[0],zinv,b0.x), fmaf(acc[1],zinv,b0.y), fmaf(acc[2],zinv,b0.z), fmaf(acc[3],zinv,b0.w),
                    fmaf(acc[4],zinv,b1.x), fmaf(acc[5],zinv,b1.y), fmaf(acc[6],zinv,b1.z), fmaf(acc[7],zinv,b1.w)};
      store8(out, n, cb, o);
    }
  } else {
    // rare fallback: 64-lane softmax, lanes 0-31 accumulate this half's channels
    float m = se;
    for (int e = beg + lane; e < end; e += 64){
      float v = a_s[cw[e].x] + ad; v = v > 0.f ? v : 0.2f*v;
      m = fmaxf(m, v);
    }
    #pragma unroll
    for (int off = 32; off; off >>= 1) m = fmaxf(m, __shfl_xor(m, off));
    float z = 0.f;
    for (int e = beg + lane; e < end; e += 64){
      float v = a_s[cw[e].x] + ad; v = v > 0.f ? v : 0.2f*v;
      z += __expf(v - m);
    }
    #pragma unroll
    for (int off = 32; off; off >>= 1) z += __shfl_xor(z, off);
    float es = __expf(se - m);
    z += es;
    float zinv = 1.0f/(z + 1e-16f);
    int c = half*32 + (lane & 31);
    float acc = (lane < 32) ? es*(float)h[(size_t)n*64 + c] : 0.f;
    for (int e = beg; e < end; ++e){
      int sj = cw[e].x;
      float v = a_s[sj] + ad; v = v > 0.f ? v : 0.2f*v;
      float w = __expf(v - m);
      if (lane < 32) acc = fmaf(w, (float)h[(size_t)sj*64 + c], acc);
    }
    if (lane < 32) out[(size_t)n*64 + c] = __float2half(acc*zinv + bias[c]);
  }
}

// ---------------- GraphNorm stats: vectorized per-block partials (fp16 t) ----------------
__global__ __launch_bounds__(256) void k_colstats(const __half* __restrict__ t,
                                                  float* __restrict__ pstats){
  int c4  = (threadIdx.x & 15)*4;
  int sub = threadIdx.x >> 4;
  float s0=0.f,s1=0.f,s2=0.f,s3=0.f, q0=0.f,q1=0.f,q2=0.f,q3=0.f;
  for (int n = blockIdx.x*16 + sub; n < NN; n += gridDim.x*16){
    uint2 u = *(const uint2*)((const __half*)t + (size_t)n*64 + c4);
    __half2 h0 = *(__half2*)&u.x, h1 = *(__half2*)&u.y;
    float2 r0 = __half22float2(h0), r1 = __half22float2(h1);
    s0 += r0.x; q0 = fmaf(r0.x, r0.x, q0);
    s1 += r0.y; q1 = fmaf(r0.y, r0.y, q1);
    s2 += r1.x; q2 = fmaf(r1.x, r1.x, q2);
    s3 += r1.y; q3 = fmaf(r1.y, r1.y, q3);
  }
  __shared__ float ls[256][4], ls2[256][4];
  ls[threadIdx.x][0]=s0; ls[threadIdx.x][1]=s1; ls[threadIdx.x][2]=s2; ls[threadIdx.x][3]=s3;
  ls2[threadIdx.x][0]=q0; ls2[threadIdx.x][1]=q1; ls2[threadIdx.x][2]=q2; ls2[threadIdx.x][3]=q3;
  __syncthreads();
  if (threadIdx.x < 16){
    int cg = threadIdx.x;
    float a0=0.f,a1=0.f,a2=0.f,a3=0.f, b0=0.f,b1=0.f,b2=0.f,b3=0.f;
    #pragma unroll
    for (int k = 0; k < 16; ++k){
      int idx = k*16 + cg;
      a0 += ls[idx][0]; a1 += ls[idx][1]; a2 += ls[idx][2]; a3 += ls[idx][3];
      b0 += ls2[idx][0]; b1 += ls2[idx][1]; b2 += ls2[idx][2]; b3 += ls2[idx][3];
    }
    int cb = cg*4;
    pstats[blockIdx.x*128 + cb    ] = a0;
    pstats[blockIdx.x*128 + cb + 1] = a1;
    pstats[blockIdx.x*128 + cb + 2] = a2;
    pstats[blockIdx.x*128 + cb + 3] = a3;
    pstats[blockIdx.x*128 + 64 + cb    ] = b0;
    pstats[blockIdx.x*128 + 64 + cb + 1] = b1;
    pstats[blockIdx.x*128 + 64 + cb + 2] = b2;
    pstats[blockIdx.x*128 + 64 + cb + 3] = b3;
  }
}

// ---------------- finalize stats: coef/shift (single block) ----------------
__global__ __launch_bounds__(256) void k_chan(const float* __restrict__ pstats,
                                              const float* __restrict__ gw,
                                              const float* __restrict__ ga,
                                              float* __restrict__ stats){
  int lane = threadIdx.x & 63, w = threadIdx.x >> 6;
  float s = 0.f, s2 = 0.f;
  for (int blk = w*(SBLK/4); blk < (w+1)*(SBLK/4); ++blk){
    s  += pstats[blk*128 + lane];
    s2 += pstats[blk*128 + 64 + lane];
  }
  __shared__ float ls[256], ls2[256];
  ls[threadIdx.x] = s; ls2[threadIdx.x] = s2;
  __syncthreads();
  if (threadIdx.x < 64){
    int c = threadIdx.x;
    s  = ls[c]  + ls[c+64]  + ls[c+128]  + ls[c+192];
    s2 = ls2[c] + ls2[c+64] + ls2[c+128] + ls2[c+192];
    const float invN = 1.0f/(float)NN;
    float m  = s*invN, ms = s2*invN, a = ga[c];
    float var = ms - m*m*a*(2.0f - a);
    stats[128 + c] = rsqrtf(var + 1e-5f)*gw[c];  // coef
    stats[192 + c] = a*m;                        // shift
  }
}

// ---------------- output head: fused resid + dot ----------------
__global__ __launch_bounds__(256) void k_outlinf(const float* __restrict__ x,
                                                 const __half* __restrict__ t,
                                                 const float* __restrict__ stats,
                                                 const float* __restrict__ gb,
                                                 const float* __restrict__ Wout,
                                                 float* __restrict__ h1){
  int lane = threadIdx.x & 63, wave = threadIdx.x >> 6;
  int n = blockIdx.x*4 + wave;
  float coef  = stats[128 + lane];
  float shift = stats[192 + lane];
  float xn = x[(size_t)n*64 + lane];
  float tv = __half2float(t[(size_t)n*64 + lane]);
  xn += lrelu01((tv - shift)*coef + gb[lane]);
  float v = xn*Wout[lane];
  #pragma unroll
  for (int off = 32; off; off >>= 1) v += __shfl_xor(v, off);
  if (lane == 0) h1[n] = v;
}

__global__ __launch_bounds__(256) void k_prop1(const float* __restrict__ h1,
                                               const int* __restrict__ rowptr,
                                               const int2* __restrict__ cw,
                                               const float* __restrict__ dinv,
                                               const float* __restrict__ b_out,
                                               float* __restrict__ xs){
  int lane = threadIdx.x & 63;
  int n = blockIdx.x*32 + (threadIdx.x >> 6)*8 + (lane >> 3);
  bool ok = n < NN;
  int beg = ok ? rowptr[n] : 0;
  int end = ok ? rowptr[n+1] : 0;
  float acc = 0.f;
  for (int e = beg + (lane & 7); e < end; e += 8){
    int2 p = cw[e];
    acc = fmaf(__int_as_float(p.y), h1[p.x], acc);
  }
  acc += __shfl_xor(acc, 1);
  acc += __shfl_xor(acc, 2);
  acc += __shfl_xor(acc, 4);
  if (ok && (lane & 7) == 0){
    float di = dinv[n];
    xs[n] = lrelu01(acc + di*di*h1[n] + b_out[0]);
  }
}

// ---------------- FC head: wide partials + parallel reduce, no atomics ----------------
__global__ __launch_bounds__(256) void k_fc1(const float* __restrict__ xs,
                                             const float* __restrict__ W,
                                             float* __restrict__ pfc){
  int j = threadIdx.x & 127, half = threadIdx.x >> 7;
  float acc = 0.f;
  for (int n = blockIdx.x*2 + half; n < NN; n += gridDim.x*2)
    acc = fmaf(xs[n], W[(size_t)n*128 + j], acc);
  __shared__ float ls[256];
  ls[threadIdx.x] = acc;
  __syncthreads();
  if (threadIdx.x < 128) pfc[blockIdx.x*128 + j] = ls[j] + ls[128 + j];
}

__global__ __launch_bounds__(256) void k_fcr(const float* __restrict__ pfc,
                                             const float* __restrict__ fc1_b,
                                             float* __restrict__ hfc){
  int j = blockIdx.x;
  int tid = threadIdx.x;
  float acc = 0.f;
  #pragma unroll
  for (int k = 0; k < FBLK/256; ++k)
    acc += pfc[(size_t)(tid + k*256)*128 + j];
  __shared__ float ls[256];
  ls[tid] = acc;
  __syncthreads();
  for (int off = 128; off > 0; off >>= 1){
    if (tid < off) ls[tid] += ls[tid + off];
    __syncthreads();
  }
  if (tid == 0){
    float v = ls[0] + fc1_b[j];
    hfc[j] = v > 0.f ? v : 0.f;
  }
}

__global__ __launch_bounds__(256) void k_fc2(const float* __restrict__ hfc,
                                             const float* __restrict__ W2,
                                             const float* __restrict__ b2,
                                             float* __restrict__ out){
  __shared__ float hs[128];
  if (threadIdx.x < 128) hs[threadIdx.x] = hfc[threadIdx.x];
  __syncthreads();
  int p = blockIdx.x*64 + (threadIdx.x >> 2);
  int q = threadIdx.x & 3;
  if (p < POI){
    float acc = 0.f;
    #pragma unroll
    for (int j = q; j < 128; j += 4)
      acc = fmaf(hs[j], W2[(size_t)j*POI + p], acc);
    acc += __shfl_xor(acc, 1);
    acc += __shfl_xor(acc, 2);
    if (q == 0){
      float v = acc + b2[p];
      out[p] = v > 0.f ? v : 0.f;
    }
  }
}

// ---------------- launch ----------------
extern "C" void kernel_launch(void* const* d_in, const int* in_sizes, int n_in,
                              void* d_out, int out_size, void* d_ws, size_t ws_size,
                              hipStream_t stream) {
  const int*   poi_idx = (const int*)d_in[0];
  const int*   cat_idx = (const int*)d_in[1];
  const float* feat    = (const float*)d_in[2];
  const int*   eidx    = (const int*)d_in[3];
  const int*   src     = eidx;
  const int*   dst     = eidx + NE;
  const float* ew      = (const float*)d_in[4];
  const float* poi_emb = (const float*)d_in[5];
  const float* cat_emb = (const float*)d_in[6];
  const float* W_in    = (const float*)d_in[7];
  const float* b_in    = (const float*)d_in[8];
  const float* gcn_W   = (const float*)d_in[9];
  const float* gcn_b   = (const float*)d_in[10];
  const float* gn_w    = (const float*)d_in[11];
  const float* gn_b    = (const float*)d_in[12];
  const float* gn_a    = (const float*)d_in[13];
  const float* gat_W   = (const float*)d_in[14];
  const float* att_s   = (const float*)d_in[15];
  const float* att_d   = (const float*)d_in[16];
  const float* gat_b   = (const float*)d_in[17];
  const float* W_out   = (const float*)d_in[18];
  const float* b_out   = (const float*)d_in[19];
  const float* fc1_W   = (const float*)d_in[20];
  const float* fc1_b   = (const float*)d_in[21];
  const float* fc2_W   = (const float*)d_in[22];
  const float* fc2_b   = (const float*)d_in[23];
  float* out = (float*)d_out;

  char* p = (char*)d_ws;
  auto alloc = [&](size_t bytes){ void* r = (void*)p; p += (bytes + 255) & ~(size_t)255; return r; };
  float*  x      = (float*) alloc((size_t)NN*64*4);
  __half* t      = (__half*)alloc((size_t)NN*64*2);
  __half* h      = (__half*)alloc((size_t)NN*64*2);
  unsigned short* partial = (unsigned short*)alloc((size_t)NWG*NN*2);  // 14.7 MB; aliased by pproj
  float*  pproj  = (float*) partial;                                   // 9.8 MB fits
  float*  cproj  = (float*) alloc((size_t)400*64*4);
  int2*   cw     = (int2*)  alloc((size_t)NE*8);
  float*  dinv   = (float*) alloc(NN*4);
  int*    counts = (int*)   alloc(NN*4);
  int*    rowptr = (int*)   alloc((NN+1)*4);
  float*  a_s    = (float*) alloc(NN*4);
  float*  a_d    = (float*) alloc(NN*4);
  float*  pstats = (float*) alloc((size_t)SBLK*128*4);
  float*  stats  = (float*) alloc(256*4);
  float*  h1     = (float*) alloc(NN*4);
  float*  xs     = (float*) alloc(NN*4);
  float*  pfc    = (float*) alloc((size_t)FBLK*128*4);
  float*  hfc    = (float*) alloc(128*4);

  const int G_N   = (NN + 255)/256;     // 150
  const int G_W4  = NN/4;               // 9583 (exact)
  const int G_PS  = 2*(NN/4);           // 19166 (channel-split props)
  const int G_L   = (NN + 31)/32;       // 1199
  const int G_PJ  = (POI + 15)/16;      // 2396
  const int G_EL  = NN*64/256;          // 9583 (exact)
  const int G_P1  = (NN + 31)/32;       // 1199
  const int G_F2  = (POI + 63)/64;      // 599

  // ---- setup: CSR build (LDS-privatized, 192 WGs, ushort partials) ----
  k_hist   <<<NWG, 1024, 0, stream>>>(dst, partial);
  k_b1     <<<G_N, 256, 0, stream>>>(partial, counts);
  k_scan   <<<1, 1024, 0, stream>>>(counts, rowptr);
  k_scatter<<<NWG, 1024, 0, stream>>>(src, dst, ew, rowptr, partial, cw);
  k_dinv   <<<G_W4, 256, 0, stream>>>(rowptr, cw, dinv);
  k_scale  <<<G_W4, 256, 0, stream>>>(rowptr, dinv, cw);

  // ---- input layer ----
  k_proj<300><<<G_PJ, 256, 0, stream>>>(poi_emb, W_in, pproj, POI);
  k_proj<100><<<25, 256, 0, stream>>>(cat_emb, W_in + 300*64, cproj, 400);
  k_gather<<<G_EL, 256, 0, stream>>>(poi_idx, cat_idx, feat, pproj, cproj, W_in + 400*64, t);
  k_gcn_prop<true, __half, float><<<G_PS, 256, 0, stream>>>(t, rowptr, cw, dinv, b_in, x);

  for (int i = 0; i < 5; i++){
    // GCN branch (previous GAT graphnorm-resid folded in for i>0)
    if (i == 0)
      k_lin64f<false,false><<<G_L, 256, 0, stream>>>(x, nullptr, nullptr, nullptr,
                                                     gcn_W, nullptr, nullptr, h, nullptr, nullptr);
    else
      k_lin64f<false,true><<<G_L, 256, 0, stream>>>(x, t, stats, gn_b + (i-1)*64,
                                                    gcn_W + i*4096, nullptr, nullptr, h, nullptr, nullptr);
    k_gcn_prop<false, __half, __half><<<G_PS, 256, 0, stream>>>(h, rowptr, cw, dinv, gcn_b + i*64, t);
    k_colstats<<<SBLK, 256, 0, stream>>>(t, pstats);
    k_chan<<<1, 256, 0, stream>>>(pstats, gn_w + i*64, gn_a + i*64, stats);
    // GAT branch (GCN graphnorm-resid folded in; attention dots fused)
    k_lin64f<true,true><<<G_L, 256, 0, stream>>>(x, t, stats, gn_b + i*64,
                                                 gat_W + i*4096, att_s + i*64, att_d + i*64, h, a_s, a_d);
    k_gat_prop<<<G_PS, 256, 0, stream>>>(h, rowptr, cw, a_s, a_d, gat_b + i*64, t);
    k_colstats<<<SBLK, 256, 0, stream>>>(t, pstats);
    k_chan<<<1, 256, 0, stream>>>(pstats, gn_w + i*64, gn_a + i*64, stats);
  }

  // ---- output head (final resid folded into the dot) ----
  k_outlinf<<<G_W4, 256, 0, stream>>>(x, t, stats, gn_b + 4*64, W_out, h1);
  k_prop1<<<G_P1, 256, 0, stream>>>(h1, rowptr, cw, dinv, b_out, xs);
  k_fc1<<<FBLK, 256, 0, stream>>>(xs, fc1_W, pfc);
  k_fcr<<<128, 256, 0, stream>>>(pfc, fc1_b, hfc);
  k_fc2<<<G_F2, 256, 0, stream>>>(hfc, fc2_W, fc2_b, out);
}

// Round 16
// 894.897 us; speedup vs baseline: 1.1776x; 1.1776x over previous
//
#include <hip/hip_runtime.h>
#include <hip/hip_fp16.h>

#define NN 38332
#define NE 1200000
#define POI 38333
#define NWG 192
#define CHUNK (NE/NWG)   // 6250 exactly
#define SBLK 256         // colstats partial blocks
#define FBLK 1024        // fc1 partial blocks

__device__ __forceinline__ float lrelu01(float v){ return v > 0.f ? v : 0.01f*v; }

__device__ __forceinline__ void load8(const __half* h, int s, int c8, float* f){
  uint4 q = *(const uint4*)((const __half*)h + (size_t)s*64 + c8);
  __half2 h0 = *(__half2*)&q.x, h1 = *(__half2*)&q.y, h2 = *(__half2*)&q.z, h3 = *(__half2*)&q.w;
  float2 r0 = __half22float2(h0), r1 = __half22float2(h1), r2 = __half22float2(h2), r3 = __half22float2(h3);
  f[0]=r0.x; f[1]=r0.y; f[2]=r1.x; f[3]=r1.y; f[4]=r2.x; f[5]=r2.y; f[6]=r3.x; f[7]=r3.y;
}
__device__ __forceinline__ void load8(const float* h, int s, int c8, float* f){
  float4 a = *(const float4*)(h + (size_t)s*64 + c8);
  float4 b = *(const float4*)(h + (size_t)s*64 + c8 + 4);
  f[0]=a.x; f[1]=a.y; f[2]=a.z; f[3]=a.w; f[4]=b.x; f[5]=b.y; f[6]=b.z; f[7]=b.w;
}
__device__ __forceinline__ void store8(float* out, int n, int cb, const float* o){
  *(float4*)&out[(size_t)n*64 + cb]     = make_float4(o[0],o[1],o[2],o[3]);
  *(float4*)&out[(size_t)n*64 + cb + 4] = make_float4(o[4],o[5],o[6],o[7]);
}
__device__ __forceinline__ void store8(__half* out, int n, int cb, const float* o){
  __half2 q0 = __floats2half2_rn(o[0], o[1]);
  __half2 q1 = __floats2half2_rn(o[2], o[3]);
  __half2 q2 = __floats2half2_rn(o[4], o[5]);
  __half2 q3 = __floats2half2_rn(o[6], o[7]);
  uint4 q;
  q.x = *(unsigned*)&q0; q.y = *(unsigned*)&q1; q.z = *(unsigned*)&q2; q.w = *(unsigned*)&q3;
  *(uint4*)((__half*)out + (size_t)n*64 + cb) = q;
}

// ---------------- setup phase A: LDS-privatized histogram (ushort partials) ----------------
__global__ __launch_bounds__(1024) void k_hist(const int* __restrict__ dst,
                                               unsigned short* __restrict__ partial){
  __shared__ int hist[NN];
  for (int i = threadIdx.x; i < NN; i += 1024) hist[i] = 0;
  __syncthreads();
  int base = blockIdx.x*CHUNK;
  for (int k = threadIdx.x; k < CHUNK; k += 1024)
    atomicAdd(&hist[dst[base + k]], 1);
  __syncthreads();
  for (int i = threadIdx.x; i < NN; i += 1024)
    partial[(size_t)blockIdx.x*NN + i] = (unsigned short)hist[i];
}

__global__ __launch_bounds__(256) void k_b1(unsigned short* __restrict__ partial,
                                            int* __restrict__ counts){
  int bin = blockIdx.x*256 + threadIdx.x;
  if (bin < NN){
    int run = 0;
    for (int wg = 0; wg < NWG; ++wg){
      int v = partial[(size_t)wg*NN + bin];
      partial[(size_t)wg*NN + bin] = (unsigned short)run;
      run += v;
    }
    counts[bin] = run;
  }
}

__global__ __launch_bounds__(1024) void k_scan(const int* __restrict__ counts, int* rowptr){
  __shared__ int part[1024];
  int tid = threadIdx.x;
  const int per = (NN + 1023)/1024;   // 38
  int base = tid*per;
  int s = 0;
  for (int k = 0; k < per; k++){ int i = base + k; if (i < NN) s += counts[i]; }
  part[tid] = s;
  __syncthreads();
  for (int off = 1; off < 1024; off <<= 1){
    int v = (tid >= off) ? part[tid-off] : 0;
    __syncthreads();
    part[tid] += v;
    __syncthreads();
  }
  int run = (tid == 0) ? 0 : part[tid-1];
  for (int k = 0; k < per; k++){
    int i = base + k;
    if (i < NN){ rowptr[i] = run; run += counts[i]; }
  }
  if (tid == 1023) rowptr[NN] = run;
}

__global__ __launch_bounds__(1024) void k_scatter(const int* __restrict__ src,
                                                  const int* __restrict__ dst,
                                                  const float* __restrict__ ew,
                                                  const int* __restrict__ rowptr,
                                                  const unsigned short* __restrict__ partial,
                                                  int2* __restrict__ cw){
  __shared__ int cur[NN];
  for (int i = threadIdx.x; i < NN; i += 1024)
    cur[i] = rowptr[i] + (int)partial[(size_t)blockIdx.x*NN + i];
  __syncthreads();
  int base = blockIdx.x*CHUNK;
  for (int k = threadIdx.x; k < CHUNK; k += 1024){
    int e = base + k;
    int d = dst[e];
    int pos = atomicAdd(&cur[d], 1);
    cw[pos] = make_int2(src[e], __float_as_int(ew[e]));
  }
}

__global__ __launch_bounds__(256) void k_dinv(const int* __restrict__ rowptr,
                                              const int2* __restrict__ cw,
                                              float* __restrict__ dinv){
  int lane = threadIdx.x & 63;
  int n = blockIdx.x*4 + (threadIdx.x >> 6);   // NN % 4 == 0
  int beg = rowptr[n], end = rowptr[n+1];
  float s = 0.f;
  for (int e = beg + lane; e < end; e += 64) s += __int_as_float(cw[e].y);
  #pragma unroll
  for (int off = 32; off; off >>= 1) s += __shfl_xor(s, off);
  if (lane == 0) dinv[n] = rsqrtf(1.0f + s);
}

__global__ __launch_bounds__(256) void k_scale(const int* __restrict__ rowptr,
                                               const float* __restrict__ dinv,
                                               int2* __restrict__ cw){
  int lane = threadIdx.x & 63;
  int n = blockIdx.x*4 + (threadIdx.x >> 6);
  float dn = dinv[n];
  int beg = rowptr[n], end = rowptr[n+1];
  for (int e = beg + lane; e < end; e += 64){
    int2 p = cw[e];
    cw[e].y = __float_as_int(dinv[p.x]*__int_as_float(p.y)*dn);
  }
}

// ---------------- dense projection: 4 rows/wave ----------------
template<int K>
__global__ __launch_bounds__(256) void k_proj(const float* __restrict__ emb,
                                              const float* __restrict__ W,
                                              float* __restrict__ outp, int rows){
  int lane = threadIdx.x & 63;
  int base = __builtin_amdgcn_readfirstlane(blockIdx.x*16 + (threadIdx.x >> 6)*4);
  float acc[4] = {0.f,0.f,0.f,0.f};
  constexpr int NCH = (K + 63)/64;
  #pragma unroll
  for (int ch = 0; ch < NCH; ++ch){
    float Wreg[64];
    #pragma unroll
    for (int j = 0; j < 64; ++j)
      Wreg[j] = (ch*64 + j < K) ? W[(ch*64 + j)*64 + lane] : 0.f;
    #pragma unroll
    for (int r = 0; r < 4; ++r){
      int row = base + r;
      if (row < rows){
        const float* er = emb + (size_t)row*K + ch*64;
        #pragma unroll
        for (int j = 0; j < 64; ++j)
          if (ch*64 + j < K) acc[r] = fmaf(er[j], Wreg[j], acc[r]);
      }
    }
  }
  #pragma unroll
  for (int r = 0; r < 4; ++r){
    int row = base + r;
    if (row < rows) outp[(size_t)row*64 + lane] = acc[r];
  }
}

__global__ __launch_bounds__(256) void k_gather(const int* __restrict__ poi_idx,
                                                const int* __restrict__ cat_idx,
                                                const float* __restrict__ feat,
                                                const float* __restrict__ pproj,
                                                const float* __restrict__ cproj,
                                                const float* __restrict__ Wf,
                                                __half* __restrict__ outh){
  int i = blockIdx.x*256 + threadIdx.x;   // NN*64 % 256 == 0
  int n = i >> 6, c = i & 63;
  float f0 = feat[n*3], f1 = feat[n*3+1], f2 = feat[n*3+2];
  float v = pproj[(size_t)poi_idx[n]*64 + c] + cproj[(size_t)cat_idx[n]*64 + c];
  v = fmaf(f0, Wf[c], v);
  v = fmaf(f1, Wf[64 + c], v);
  v = fmaf(f2, Wf[128 + c], v);
  outh[i] = __float2half(v);
}

// ---------------- fused [graphnorm-residual] + 64x64 linear (+ att dots), fp16 h out ----------------
template<bool ATT, bool RESID>
__global__ __launch_bounds__(256) void k_lin64f(float* __restrict__ x,
                                                const __half* __restrict__ t,
                                                const float* __restrict__ stats,
                                                const float* __restrict__ gb,
                                                const float* __restrict__ W,
                                                const float* __restrict__ att_src,
                                                const float* __restrict__ att_dst,
                                                __half* __restrict__ h,
                                                float* __restrict__ a_s,
                                                float* __restrict__ a_d){
  int lane = threadIdx.x & 63;
  int base = blockIdx.x*32 + (threadIdx.x >> 6)*8;
  float Wreg[64];
  #pragma unroll
  for (int j = 0; j < 64; ++j) Wreg[j] = W[j*64 + lane];
  float coef = 0.f, shift = 0.f, gbv = 0.f;
  if (RESID){
    coef  = stats[128 + lane];
    shift = stats[192 + lane];
    gbv   = gb[lane];
  }
  float as_l = 0.f, ad_l = 0.f;
  if (ATT){ as_l = att_src[lane]; ad_l = att_dst[lane]; }
  #pragma unroll
  for (int r = 0; r < 8; ++r){
    int row = base + r;
    if (row < NN){
      float xn = x[(size_t)row*64 + lane];
      if (RESID){
        float tv = __half2float(t[(size_t)row*64 + lane]);
        xn += lrelu01((tv - shift)*coef + gbv);
        x[(size_t)row*64 + lane] = xn;
      }
      int xi = __float_as_int(xn);
      float acc = 0.f;
      #pragma unroll
      for (int j = 0; j < 64; ++j)
        acc = fmaf(__int_as_float(__builtin_amdgcn_readlane(xi, j)), Wreg[j], acc);
      h[(size_t)row*64 + lane] = __float2half(acc);
      if (ATT){
        float s1 = acc*as_l, s2 = acc*ad_l;
        #pragma unroll
        for (int off = 32; off; off >>= 1){ s1 += __shfl_xor(s1, off); s2 += __shfl_xor(s2, off); }
        if (lane == 0){ a_s[row] = s1; a_d[row] = s2; }
      }
    }
  }
}

// ---------------- GCN propagation: 16 edge-slots/iter, 4 loads in flight (R14-proven) ----------------
template<bool DO_LRELU, typename TIN, typename TOUT>
__global__ __launch_bounds__(256) void k_gcn_prop(const TIN* __restrict__ h,
                                                  const int* __restrict__ rowptr,
                                                  const int2* __restrict__ cw,
                                                  const float* __restrict__ dinv,
                                                  const float* __restrict__ bias,
                                                  TOUT* __restrict__ out){
  int lane = threadIdx.x & 63;
  int n = __builtin_amdgcn_readfirstlane(blockIdx.x*4 + (threadIdx.x >> 6));
  int beg = rowptr[n], end = rowptr[n+1];
  int deg = end - beg;
  int g  = lane >> 3;
  int c8 = (lane & 7) << 3;
  float acc[8] = {0.f,0.f,0.f,0.f,0.f,0.f,0.f,0.f};
  float acc2[8] = {0.f,0.f,0.f,0.f,0.f,0.f,0.f,0.f};
  if (deg < 64){
    int sv = n; float wv = 0.f;
    if (lane < deg){
      int2 p = cw[beg + lane];
      sv = p.x; wv = __int_as_float(p.y);
    } else if (lane == deg){
      float di = dinv[n];
      wv = di*di;
    }
    int ne = deg + 1;
    int nit = (ne + 15) >> 4;
    float wA0 = __shfl(wv, g),     wB0 = __shfl(wv, 8 + g);
    int   sA0 = __shfl(sv, g),     sB0 = __shfl(sv, 8 + g);
    float fA0[8], fB0[8];
    load8(h, sA0, c8, fA0); load8(h, sB0, c8, fB0);
    for (int it = 1; it < nit; ++it){
      int eiA = (it << 4) + g, eiB = eiA + 8;
      float wA1 = __shfl(wv, eiA), wB1 = __shfl(wv, eiB);
      int   sA1 = __shfl(sv, eiA), sB1 = __shfl(sv, eiB);
      float fA1[8], fB1[8];
      load8(h, sA1, c8, fA1); load8(h, sB1, c8, fB1);
      #pragma unroll
      for (int j = 0; j < 8; ++j){
        acc[j]  = fmaf(wA0, fA0[j], acc[j]);
        acc2[j] = fmaf(wB0, fB0[j], acc2[j]);
      }
      wA0 = wA1; wB0 = wB1;
      #pragma unroll
      for (int j = 0; j < 8; ++j){ fA0[j] = fA1[j]; fB0[j] = fB1[j]; }
    }
    #pragma unroll
    for (int j = 0; j < 8; ++j){
      acc[j]  = fmaf(wA0, fA0[j], acc[j]);
      acc2[j] = fmaf(wB0, fB0[j], acc2[j]);
    }
  } else {
    {
      float di = dinv[n];
      float w = (g == 0) ? di*di : 0.f;
      float f[8]; load8(h, n, c8, f);
      #pragma unroll
      for (int j = 0; j < 8; ++j) acc[j] = fmaf(w, f[j], acc[j]);
    }
    int nit = (deg + 7) >> 3;
    for (int it = 0; it < nit; ++it){
      int ei = (it << 3) + g;
      int2 p = cw[beg + (ei < deg ? ei : 0)];
      float w = (ei < deg) ? __int_as_float(p.y) : 0.f;
      float f[8]; load8(h, p.x, c8, f);
      #pragma unroll
      for (int j = 0; j < 8; ++j) acc[j] = fmaf(w, f[j], acc[j]);
    }
  }
  #pragma unroll
  for (int j = 0; j < 8; ++j) acc[j] += acc2[j];
  #pragma unroll
  for (int m = 8; m < 64; m <<= 1){
    #pragma unroll
    for (int j = 0; j < 8; ++j) acc[j] += __shfl_xor(acc[j], m);
  }
  if (lane < 8){
    int cb = lane << 3;
    float4 b0 = *(const float4*)&bias[cb];
    float4 b1 = *(const float4*)&bias[cb + 4];
    float o[8] = {acc[0]+b0.x, acc[1]+b0.y, acc[2]+b0.z, acc[3]+b0.w,
                  acc[4]+b1.x, acc[5]+b1.y, acc[6]+b1.z, acc[7]+b1.w};
    if (DO_LRELU){
      #pragma unroll
      for (int j = 0; j < 8; ++j) o[j] = lrelu01(o[j]);
    }
    store8(out, n, cb, o);
  }
}

// ---------------- GAT propagation: lane-per-edge softmax, 16-slot pipelined accumulate (R14-proven) ----------------
__global__ __launch_bounds__(256) void k_gat_prop(const __half* __restrict__ h,
                                                  const int* __restrict__ rowptr,
                                                  const int2* __restrict__ cw,
                                                  const float* __restrict__ a_s,
                                                  const float* __restrict__ a_d,
                                                  const float* __restrict__ bias,
                                                  __half* __restrict__ out){
  int lane = threadIdx.x & 63;
  int n = __builtin_amdgcn_readfirstlane(blockIdx.x*4 + (threadIdx.x >> 6));
  int beg = rowptr[n], end = rowptr[n+1];
  int deg = end - beg;
  float ad = a_d[n];
  float se = a_s[n] + ad; se = se > 0.f ? se : 0.2f*se;
  if (deg <= 64){
    int s = 0; float v = -1e30f;
    if (lane < deg){
      s = cw[beg + lane].x;
      v = a_s[s] + ad; v = v > 0.f ? v : 0.2f*v;
    }
    float m = fmaxf(se, v);
    #pragma unroll
    for (int off = 32; off; off >>= 1) m = fmaxf(m, __shfl_xor(m, off));
    float ev = (lane < deg) ? __expf(v - m) : 0.f;
    float z = ev;
    #pragma unroll
    for (int off = 32; off; off >>= 1) z += __shfl_xor(z, off);
    float es = __expf(se - m);
    z += es;
    float zinv = 1.0f/(z + 1e-16f);
    int g = lane >> 3, c8 = (lane & 7) << 3;
    float acc[8] = {0.f,0.f,0.f,0.f,0.f,0.f,0.f,0.f};
    float acc2[8] = {0.f,0.f,0.f,0.f,0.f,0.f,0.f,0.f};
    { float f[8]; load8(h, n, c8, f);
      float w = (g == 0) ? es : 0.f;
      #pragma unroll
      for (int j = 0; j < 8; ++j) acc[j] = fmaf(w, f[j], acc[j]);
    }
    int nit = (deg + 15) >> 4;
    if (nit > 0){
      float wA0 = __shfl(ev, g),     wB0 = __shfl(ev, 8 + g);
      int   sA0 = __shfl(s,  g),     sB0 = __shfl(s,  8 + g);
      float fA0[8], fB0[8];
      load8(h, sA0, c8, fA0); load8(h, sB0, c8, fB0);
      for (int it = 1; it < nit; ++it){
        int eiA = (it << 4) + g, eiB = eiA + 8;
        float wA1 = __shfl(ev, eiA), wB1 = __shfl(ev, eiB);
        int   sA1 = __shfl(s,  eiA), sB1 = __shfl(s,  eiB);
        float fA1[8], fB1[8];
        load8(h, sA1, c8, fA1); load8(h, sB1, c8, fB1);
        #pragma unroll
        for (int j = 0; j < 8; ++j){
          acc[j]  = fmaf(wA0, fA0[j], acc[j]);
          acc2[j] = fmaf(wB0, fB0[j], acc2[j]);
        }
        wA0 = wA1; wB0 = wB1;
        #pragma unroll
        for (int j = 0; j < 8; ++j){ fA0[j] = fA1[j]; fB0[j] = fB1[j]; }
      }
      #pragma unroll
      for (int j = 0; j < 8; ++j){
        acc[j]  = fmaf(wA0, fA0[j], acc[j]);
        acc2[j] = fmaf(wB0, fB0[j], acc2[j]);
      }
    }
    #pragma unroll
    for (int j = 0; j < 8; ++j) acc[j] += acc2[j];
    #pragma unroll
    for (int mm = 8; mm < 64; mm <<= 1){
      #pragma unroll
      for (int j = 0; j < 8; ++j) acc[j] += __shfl_xor(acc[j], mm);
    }
    if (lane < 8){
      int cb = lane << 3;
      float4 b0 = *(const float4*)&bias[cb];
      float4 b1 = *(const float4*)&bias[cb + 4];
      float o[8] = {fmaf(acc[0],zinv,b0.x), fmaf(acc[1],zinv,b0.y), fmaf(acc[2],zinv,b0.z), fmaf(acc[3],zinv,b0.w),
                    fmaf(acc[4],zinv,b1.x), fmaf(acc[5],zinv,b1.y), fmaf(acc[6],zinv,b1.z), fmaf(acc[7],zinv,b1.w)};
      store8(out, n, cb, o);
    }
  } else {
    float m = se;
    for (int e = beg + lane; e < end; e += 64){
      float v = a_s[cw[e].x] + ad; v = v > 0.f ? v : 0.2f*v;
      m = fmaxf(m, v);
    }
    #pragma unroll
    for (int off = 32; off; off >>= 1) m = fmaxf(m, __shfl_xor(m, off));
    float z = 0.f;
    for (int e = beg + lane; e < end; e += 64){
      float v = a_s[cw[e].x] + ad; v = v > 0.f ? v : 0.2f*v;
      z += __expf(v - m);
    }
    #pragma unroll
    for (int off = 32; off; off >>= 1) z += __shfl_xor(z, off);
    float es = __expf(se - m);
    z += es;
    float zinv = 1.0f/(z + 1e-16f);
    float acc = es*(float)h[(size_t)n*64 + lane];
    for (int e = beg; e < end; ++e){
      int sj = cw[e].x;
      float v = a_s[sj] + ad; v = v > 0.f ? v : 0.2f*v;
      acc = fmaf(__expf(v - m), (float)h[(size_t)sj*64 + lane], acc);
    }
    out[(size_t)n*64 + lane] = __float2half(acc*zinv + bias[lane]);
  }
}

// ---------------- GraphNorm stats: vectorized per-block partials (fp16 t) ----------------
__global__ __launch_bounds__(256) void k_colstats(const __half* __restrict__ t,
                                                  float* __restrict__ pstats){
  int c4  = (threadIdx.x & 15)*4;
  int sub = threadIdx.x >> 4;
  float s0=0.f,s1=0.f,s2=0.f,s3=0.f, q0=0.f,q1=0.f,q2=0.f,q3=0.f;
  for (int n = blockIdx.x*16 + sub; n < NN; n += gridDim.x*16){
    uint2 u = *(const uint2*)((const __half*)t + (size_t)n*64 + c4);
    __half2 h0 = *(__half2*)&u.x, h1 = *(__half2*)&u.y;
    float2 r0 = __half22float2(h0), r1 = __half22float2(h1);
    s0 += r0.x; q0 = fmaf(r0.x, r0.x, q0);
    s1 += r0.y; q1 = fmaf(r0.y, r0.y, q1);
    s2 += r1.x; q2 = fmaf(r1.x, r1.x, q2);
    s3 += r1.y; q3 = fmaf(r1.y, r1.y, q3);
  }
  __shared__ float ls[256][4], ls2[256][4];
  ls[threadIdx.x][0]=s0; ls[threadIdx.x][1]=s1; ls[threadIdx.x][2]=s2; ls[threadIdx.x][3]=s3;
  ls2[threadIdx.x][0]=q0; ls2[threadIdx.x][1]=q1; ls2[threadIdx.x][2]=q2; ls2[threadIdx.x][3]=q3;
  __syncthreads();
  if (threadIdx.x < 16){
    int cg = threadIdx.x;
    float a0=0.f,a1=0.f,a2=0.f,a3=0.f, b0=0.f,b1=0.f,b2=0.f,b3=0.f;
    #pragma unroll
    for (int k = 0; k < 16; ++k){
      int idx = k*16 + cg;
      a0 += ls[idx][0]; a1 += ls[idx][1]; a2 += ls[idx][2]; a3 += ls[idx][3];
      b0 += ls2[idx][0]; b1 += ls2[idx][1]; b2 += ls2[idx][2]; b3 += ls2[idx][3];
    }
    int cb = cg*4;
    pstats[blockIdx.x*128 + cb    ] = a0;
    pstats[blockIdx.x*128 + cb + 1] = a1;
    pstats[blockIdx.x*128 + cb + 2] = a2;
    pstats[blockIdx.x*128 + cb + 3] = a3;
    pstats[blockIdx.x*128 + 64 + cb    ] = b0;
    pstats[blockIdx.x*128 + 64 + cb + 1] = b1;
    pstats[blockIdx.x*128 + 64 + cb + 2] = b2;
    pstats[blockIdx.x*128 + 64 + cb + 3] = b3;
  }
}

// ---------------- finalize stats: coef/shift (single block) ----------------
__global__ __launch_bounds__(256) void k_chan(const float* __restrict__ pstats,
                                              const float* __restrict__ gw,
                                              const float* __restrict__ ga,
                                              float* __restrict__ stats){
  int lane = threadIdx.x & 63, w = threadIdx.x >> 6;
  float s = 0.f, s2 = 0.f;
  for (int blk = w*(SBLK/4); blk < (w+1)*(SBLK/4); ++blk){
    s  += pstats[blk*128 + lane];
    s2 += pstats[blk*128 + 64 + lane];
  }
  __shared__ float ls[256], ls2[256];
  ls[threadIdx.x] = s; ls2[threadIdx.x] = s2;
  __syncthreads();
  if (threadIdx.x < 64){
    int c = threadIdx.x;
    s  = ls[c]  + ls[c+64]  + ls[c+128]  + ls[c+192];
    s2 = ls2[c] + ls2[c+64] + ls2[c+128] + ls2[c+192];
    const float invN = 1.0f/(float)NN;
    float m  = s*invN, ms = s2*invN, a = ga[c];
    float var = ms - m*m*a*(2.0f - a);
    stats[128 + c] = rsqrtf(var + 1e-5f)*gw[c];  // coef
    stats[192 + c] = a*m;                        // shift
  }
}

// ---------------- output head: fused resid + dot ----------------
__global__ __launch_bounds__(256) void k_outlinf(const float* __restrict__ x,
                                                 const __half* __restrict__ t,
                                                 const float* __restrict__ stats,
                                                 const float* __restrict__ gb,
                                                 const float* __restrict__ Wout,
                                                 float* __restrict__ h1){
  int lane = threadIdx.x & 63, wave = threadIdx.x >> 6;
  int n = blockIdx.x*4 + wave;
  float coef  = stats[128 + lane];
  float shift = stats[192 + lane];
  float xn = x[(size_t)n*64 + lane];
  float tv = __half2float(t[(size_t)n*64 + lane]);
  xn += lrelu01((tv - shift)*coef + gb[lane]);
  float v = xn*Wout[lane];
  #pragma unroll
  for (int off = 32; off; off >>= 1) v += __shfl_xor(v, off);
  if (lane == 0) h1[n] = v;
}

__global__ __launch_bounds__(256) void k_prop1(const float* __restrict__ h1,
                                               const int* __restrict__ rowptr,
                                               const int2* __restrict__ cw,
                                               const float* __restrict__ dinv,
                                               const float* __restrict__ b_out,
                                               float* __restrict__ xs){
  int lane = threadIdx.x & 63;
  int n = blockIdx.x*32 + (threadIdx.x >> 6)*8 + (lane >> 3);
  bool ok = n < NN;
  int beg = ok ? rowptr[n] : 0;
  int end = ok ? rowptr[n+1] : 0;
  float acc = 0.f;
  for (int e = beg + (lane & 7); e < end; e += 8){
    int2 p = cw[e];
    acc = fmaf(__int_as_float(p.y), h1[p.x], acc);
  }
  acc += __shfl_xor(acc, 1);
  acc += __shfl_xor(acc, 2);
  acc += __shfl_xor(acc, 4);
  if (ok && (lane & 7) == 0){
    float di = dinv[n];
    xs[n] = lrelu01(acc + di*di*h1[n] + b_out[0]);
  }
}

// ---------------- FC head: wide partials + parallel reduce, no atomics ----------------
__global__ __launch_bounds__(256) void k_fc1(const float* __restrict__ xs,
                                             const float* __restrict__ W,
                                             float* __restrict__ pfc){
  int j = threadIdx.x & 127, half = threadIdx.x >> 7;
  float acc = 0.f;
  for (int n = blockIdx.x*2 + half; n < NN; n += gridDim.x*2)
    acc = fmaf(xs[n], W[(size_t)n*128 + j], acc);
  __shared__ float ls[256];
  ls[threadIdx.x] = acc;
  __syncthreads();
  if (threadIdx.x < 128) pfc[blockIdx.x*128 + j] = ls[j] + ls[128 + j];
}

__global__ __launch_bounds__(256) void k_fcr(const float* __restrict__ pfc,
                                             const float* __restrict__ fc1_b,
                                             float* __restrict__ hfc){
  int j = blockIdx.x;
  int tid = threadIdx.x;
  float acc = 0.f;
  #pragma unroll
  for (int k = 0; k < FBLK/256; ++k)
    acc += pfc[(size_t)(tid + k*256)*128 + j];
  __shared__ float ls[256];
  ls[tid] = acc;
  __syncthreads();
  for (int off = 128; off > 0; off >>= 1){
    if (tid < off) ls[tid] += ls[tid + off];
    __syncthreads();
  }
  if (tid == 0){
    float v = ls[0] + fc1_b[j];
    hfc[j] = v > 0.f ? v : 0.f;
  }
}

__global__ __launch_bounds__(256) void k_fc2(const float* __restrict__ hfc,
                                             const float* __restrict__ W2,
                                             const float* __restrict__ b2,
                                             float* __restrict__ out){
  __shared__ float hs[128];
  if (threadIdx.x < 128) hs[threadIdx.x] = hfc[threadIdx.x];
  __syncthreads();
  int p = blockIdx.x*64 + (threadIdx.x >> 2);
  int q = threadIdx.x & 3;
  if (p < POI){
    float acc = 0.f;
    #pragma unroll
    for (int j = q; j < 128; j += 4)
      acc = fmaf(hs[j], W2[(size_t)j*POI + p], acc);
    acc += __shfl_xor(acc, 1);
    acc += __shfl_xor(acc, 2);
    if (q == 0){
      float v = acc + b2[p];
      out[p] = v > 0.f ? v : 0.f;
    }
  }
}

// ---------------- launch ----------------
extern "C" void kernel_launch(void* const* d_in, const int* in_sizes, int n_in,
                              void* d_out, int out_size, void* d_ws, size_t ws_size,
                              hipStream_t stream) {
  const int*   poi_idx = (const int*)d_in[0];
  const int*   cat_idx = (const int*)d_in[1];
  const float* feat    = (const float*)d_in[2];
  const int*   eidx    = (const int*)d_in[3];
  const int*   src     = eidx;
  const int*   dst     = eidx + NE;
  const float* ew      = (const float*)d_in[4];
  const float* poi_emb = (const float*)d_in[5];
  const float* cat_emb = (const float*)d_in[6];
  const float* W_in    = (const float*)d_in[7];
  const float* b_in    = (const float*)d_in[8];
  const float* gcn_W   = (const float*)d_in[9];
  const float* gcn_b   = (const float*)d_in[10];
  const float* gn_w    = (const float*)d_in[11];
  const float* gn_b    = (const float*)d_in[12];
  const float* gn_a    = (const float*)d_in[13];
  const float* gat_W   = (const float*)d_in[14];
  const float* att_s   = (const float*)d_in[15];
  const float* att_d   = (const float*)d_in[16];
  const float* gat_b   = (const float*)d_in[17];
  const float* W_out   = (const float*)d_in[18];
  const float* b_out   = (const float*)d_in[19];
  const float* fc1_W   = (const float*)d_in[20];
  const float* fc1_b   = (const float*)d_in[21];
  const float* fc2_W   = (const float*)d_in[22];
  const float* fc2_b   = (const float*)d_in[23];
  float* out = (float*)d_out;

  char* p = (char*)d_ws;
  auto alloc = [&](size_t bytes){ void* r = (void*)p; p += (bytes + 255) & ~(size_t)255; return r; };
  float*  x      = (float*) alloc((size_t)NN*64*4);
  __half* t      = (__half*)alloc((size_t)NN*64*2);
  __half* h      = (__half*)alloc((size_t)NN*64*2);
  unsigned short* partial = (unsigned short*)alloc((size_t)NWG*NN*2);  // 14.7 MB; aliased by pproj
  float*  pproj  = (float*) partial;                                   // 9.8 MB fits
  float*  cproj  = (float*) alloc((size_t)400*64*4);
  int2*   cw     = (int2*)  alloc((size_t)NE*8);
  float*  dinv   = (float*) alloc(NN*4);
  int*    counts = (int*)   alloc(NN*4);
  int*    rowptr = (int*)   alloc((NN+1)*4);
  float*  a_s    = (float*) alloc(NN*4);
  float*  a_d    = (float*) alloc(NN*4);
  float*  pstats = (float*) alloc((size_t)SBLK*128*4);
  float*  stats  = (float*) alloc(256*4);
  float*  h1     = (float*) alloc(NN*4);
  float*  xs     = (float*) alloc(NN*4);
  float*  pfc    = (float*) alloc((size_t)FBLK*128*4);
  float*  hfc    = (float*) alloc(128*4);

  const int G_N   = (NN + 255)/256;     // 150
  const int G_W4  = NN/4;               // 9583 (exact)
  const int G_L   = (NN + 31)/32;       // 1199
  const int G_PJ  = (POI + 15)/16;      // 2396
  const int G_EL  = NN*64/256;          // 9583 (exact)
  const int G_P1  = (NN + 31)/32;       // 1199
  const int G_F2  = (POI + 63)/64;      // 599

  // ---- setup: CSR build (LDS-privatized, 192 WGs, ushort partials) ----
  k_hist   <<<NWG, 1024, 0, stream>>>(dst, partial);
  k_b1     <<<G_N, 256, 0, stream>>>(partial, counts);
  k_scan   <<<1, 1024, 0, stream>>>(counts, rowptr);
  k_scatter<<<NWG, 1024, 0, stream>>>(src, dst, ew, rowptr, partial, cw);
  k_dinv   <<<G_W4, 256, 0, stream>>>(rowptr, cw, dinv);
  k_scale  <<<G_W4, 256, 0, stream>>>(rowptr, dinv, cw);

  // ---- input layer ----
  k_proj<300><<<G_PJ, 256, 0, stream>>>(poi_emb, W_in, pproj, POI);
  k_proj<100><<<25, 256, 0, stream>>>(cat_emb, W_in + 300*64, cproj, 400);
  k_gather<<<G_EL, 256, 0, stream>>>(poi_idx, cat_idx, feat, pproj, cproj, W_in + 400*64, t);
  k_gcn_prop<true, __half, float><<<G_W4, 256, 0, stream>>>(t, rowptr, cw, dinv, b_in, x);

  for (int i = 0; i < 5; i++){
    // GCN branch (previous GAT graphnorm-resid folded in for i>0)
    if (i == 0)
      k_lin64f<false,false><<<G_L, 256, 0, stream>>>(x, nullptr, nullptr, nullptr,
                                                     gcn_W, nullptr, nullptr, h, nullptr, nullptr);
    else
      k_lin64f<false,true><<<G_L, 256, 0, stream>>>(x, t, stats, gn_b + (i-1)*64,
                                                    gcn_W + i*4096, nullptr, nullptr, h, nullptr, nullptr);
    k_gcn_prop<false, __half, __half><<<G_W4, 256, 0, stream>>>(h, rowptr, cw, dinv, gcn_b + i*64, t);
    k_colstats<<<SBLK, 256, 0, stream>>>(t, pstats);
    k_chan<<<1, 256, 0, stream>>>(pstats, gn_w + i*64, gn_a + i*64, stats);
    // GAT branch (GCN graphnorm-resid folded in; attention dots fused)
    k_lin64f<true,true><<<G_L, 256, 0, stream>>>(x, t, stats, gn_b + i*64,
                                                 gat_W + i*4096, att_s + i*64, att_d + i*64, h, a_s, a_d);
    k_gat_prop<<<G_W4, 256, 0, stream>>>(h, rowptr, cw, a_s, a_d, gat_b + i*64, t);
    k_colstats<<<SBLK, 256, 0, stream>>>(t, pstats);
    k_chan<<<1, 256, 0, stream>>>(pstats, gn_w + i*64, gn_a + i*64, stats);
  }

  // ---- output head (final resid folded into the dot) ----
  k_outlinf<<<G_W4, 256, 0, stream>>>(x, t, stats, gn_b + 4*64, W_out, h1);
  k_prop1<<<G_P1, 256, 0, stream>>>(h1, rowptr, cw, dinv, b_out, xs);
  k_fc1<<<FBLK, 256, 0, stream>>>(xs, fc1_W, pfc);
  k_fcr<<<128, 256, 0, stream>>>(pfc, fc1_b, hfc);
  k_fc2<<<G_F2, 256, 0, stream>>>(hfc, fc2_W, fc2_b, out);
}